// Round 2
// baseline (1716.625 us; speedup 1.0000x reference)
//
#include <hip/hip_runtime.h>
#include <math.h>

#define NSEG 440
#define CF   2112
#define HW   65536
#define NH   1024

typedef float f32x4 __attribute__((ext_vector_type(4)));
typedef int   i32x4 __attribute__((ext_vector_type(4)));

// ---------------- ws layout (floats) ----------------
#define OFF_HIST 0        // 1320 (padded to 1344)
#define OFF_DOT  1344     // 193600 (440*440) -> end 194944
#define OFF_INVN 194944   // 448
#define OFF_LAB  195392   // 448 (ints)
#define OFF_FEAT 195840   // 929280 (440*2112)
#define OFF_H1   1125120  // 450560
#define OFF_H2   1575680  // 450560 -> end 2026240 floats (8.1 MB)

// ---------------- histogram of y per segment (also gives counts) -------------
__global__ __launch_bounds__(256) void hist_kernel(const int* __restrict__ sp,
                                                   const int* __restrict__ y,
                                                   float* __restrict__ hist) {
    __shared__ float lh[NSEG * 3];
    int t = threadIdx.x;
    for (int i = t; i < NSEG * 3; i += 256) lh[i] = 0.0f;
    __syncthreads();
    int tid = blockIdx.x * 256 + t;   // 16 blocks -> 4096 threads
#pragma unroll
    for (int k = 0; k < 4; ++k) {
        int chunk = tid + k * 4096;   // 16384 int4 chunks total
        i32x4 s4 = *(const i32x4*)(sp + (size_t)chunk * 4);
        i32x4 y4 = *(const i32x4*)(y  + (size_t)chunk * 4);
        atomicAdd(&lh[s4.x * 3 + y4.x], 1.0f);
        atomicAdd(&lh[s4.y * 3 + y4.y], 1.0f);
        atomicAdd(&lh[s4.z * 3 + y4.z], 1.0f);
        atomicAdd(&lh[s4.w * 3 + y4.w], 1.0f);
    }
    __syncthreads();
    for (int i = t; i < NSEG * 3; i += 256) {
        float v = lh[i];
        if (v != 0.0f) atomicAdd(&hist[i], v);
    }
}

// ---------------- per-channel segment mean -> feat ---------------------------
// 1 block per channel; unroll x8 so 16 independent global loads are in flight
// per wave (16 KB) -> latency-hiding instead of round-1's 2 KB.
__global__ __launch_bounds__(256) void segsum_kernel(const float* __restrict__ fm,
                                                     const int* __restrict__ sp,
                                                     const float* __restrict__ hist,
                                                     float* __restrict__ feat) {
    __shared__ float seg[NSEG];
    int t = threadIdx.x;
    int c = blockIdx.x;
    for (int s = t; s < NSEG; s += 256) seg[s] = 0.0f;
    __syncthreads();
    const float* f = fm + (size_t)c * HW;
#pragma unroll 1
    for (int it = 0; it < 8; ++it) {
        f32x4 v[8];
        i32x4 q[8];
#pragma unroll
        for (int u = 0; u < 8; ++u) {
            int p = (it * 8 + u) * 1024 + t * 4;
            v[u] = *(const f32x4*)(f + p);
            q[u] = *(const i32x4*)(sp + p);
        }
#pragma unroll
        for (int u = 0; u < 8; ++u) {
            atomicAdd(&seg[q[u].x], v[u].x);
            atomicAdd(&seg[q[u].y], v[u].y);
            atomicAdd(&seg[q[u].z], v[u].z);
            atomicAdd(&seg[q[u].w], v[u].w);
        }
    }
    __syncthreads();
    for (int s = t; s < NSEG; s += 256) {
        float cnt = hist[3 * s] + hist[3 * s + 1] + hist[3 * s + 2];
        feat[(size_t)s * CF + c] = seg[s] / fmaxf(cnt, 1.0f);
    }
}

// ---------------- labels from histogram (argmax, first-max ties) -------------
__global__ void lab_kernel(const float* __restrict__ hist, int* __restrict__ lab) {
    int s = blockIdx.x * 256 + threadIdx.x;
    if (s >= NSEG) return;
    float h0 = hist[3 * s], h1 = hist[3 * s + 1], h2 = hist[3 * s + 2];
    int l = 0; float b = h0;
    if (h1 > b) { l = 1; b = h1; }
    if (h2 > b) { l = 2; b = h2; }
    if (l == 0) l = (h2 > h1) ? 2 : ((h1 > h2) ? 1 : 0);
    lab[s] = l;
}

// ---------------- split-K fp32 GEMM: C += A(MxK) @ B(KxN), atomic output -----
// 128x128 tile, 256 threads, 8x8 per thread. blockIdx.z = k-slice.
__global__ __launch_bounds__(256) void gemm_nn_atomic(const float* __restrict__ A,
                                                      const float* __restrict__ B,
                                                      float* __restrict__ C,
                                                      int M, int N, int K, int kslice) {
    __shared__ __align__(16) float As[16][128];
    __shared__ __align__(16) float Bs[16][128];
    int t  = threadIdx.x;
    int n0 = blockIdx.x * 128;
    int m0 = blockIdx.y * 128;
    int kbeg = blockIdx.z * kslice;
    int kend = kbeg + kslice;
    int tx = t & 15, ty = t >> 4;
    float acc[8][8] = {};
    for (int k0 = kbeg; k0 < kend; k0 += 16) {
#pragma unroll
        for (int i = 0; i < 2; ++i) {         // A: 128 rows x 16 cols, transposed
            int slot = t * 2 + i;             // 0..511
            int row = slot >> 2, c4 = (slot & 3) * 4;
            int gm = m0 + row;
            f32x4 v = (gm < M) ? *(const f32x4*)(A + (size_t)gm * K + k0 + c4)
                               : (f32x4)(0.0f);
            As[c4 + 0][row] = v.x;
            As[c4 + 1][row] = v.y;
            As[c4 + 2][row] = v.z;
            As[c4 + 3][row] = v.w;
        }
#pragma unroll
        for (int i = 0; i < 2; ++i) {         // B: 16 rows x 128 cols, direct
            int slot = t * 2 + i;
            int kk = slot >> 5, c4 = (slot & 31) * 4;
            f32x4 v = *(const f32x4*)(B + (size_t)(k0 + kk) * N + n0 + c4);
            *(f32x4*)&Bs[kk][c4] = v;
        }
        __syncthreads();
#pragma unroll
        for (int kk = 0; kk < 16; ++kk) {
            float a[8], b[8];
            *(f32x4*)&a[0] = *(const f32x4*)&As[kk][ty * 8];
            *(f32x4*)&a[4] = *(const f32x4*)&As[kk][ty * 8 + 4];
            *(f32x4*)&b[0] = *(const f32x4*)&Bs[kk][tx * 8];
            *(f32x4*)&b[4] = *(const f32x4*)&Bs[kk][tx * 8 + 4];
#pragma unroll
            for (int i = 0; i < 8; ++i)
#pragma unroll
                for (int j = 0; j < 8; ++j) acc[i][j] += a[i] * b[j];
        }
        __syncthreads();
    }
#pragma unroll
    for (int i = 0; i < 8; ++i) {
        int m = m0 + ty * 8 + i;
        if (m < M) {
#pragma unroll
            for (int j = 0; j < 8; ++j)
                atomicAdd(&C[(size_t)m * N + n0 + tx * 8 + j], acc[i][j]);
        }
    }
}

// ---------------- split-K NT GEMM: dot += feat @ featT (440x440) -------------
__global__ __launch_bounds__(256) void gemm_nt_atomic(const float* __restrict__ A,
                                                      float* __restrict__ C,
                                                      int M, int K, int kslice) {
    __shared__ __align__(16) float As[16][128];
    __shared__ __align__(16) float Bs[16][128];
    int t  = threadIdx.x;
    int n0 = blockIdx.x * 128;
    int m0 = blockIdx.y * 128;
    int kbeg = blockIdx.z * kslice;
    int kend = kbeg + kslice;
    int tx = t & 15, ty = t >> 4;
    float acc[8][8] = {};
    for (int k0 = kbeg; k0 < kend; k0 += 16) {
#pragma unroll
        for (int i = 0; i < 2; ++i) {
            int slot = t * 2 + i;
            int row = slot >> 2, c4 = (slot & 3) * 4;
            int gm = m0 + row;
            f32x4 v = (gm < M) ? *(const f32x4*)(A + (size_t)gm * K + k0 + c4)
                               : (f32x4)(0.0f);
            As[c4 + 0][row] = v.x;
            As[c4 + 1][row] = v.y;
            As[c4 + 2][row] = v.z;
            As[c4 + 3][row] = v.w;
            int gn = n0 + row;
            f32x4 w = (gn < M) ? *(const f32x4*)(A + (size_t)gn * K + k0 + c4)
                               : (f32x4)(0.0f);
            Bs[c4 + 0][row] = w.x;
            Bs[c4 + 1][row] = w.y;
            Bs[c4 + 2][row] = w.z;
            Bs[c4 + 3][row] = w.w;
        }
        __syncthreads();
#pragma unroll
        for (int kk = 0; kk < 16; ++kk) {
            float a[8], b[8];
            *(f32x4*)&a[0] = *(const f32x4*)&As[kk][ty * 8];
            *(f32x4*)&a[4] = *(const f32x4*)&As[kk][ty * 8 + 4];
            *(f32x4*)&b[0] = *(const f32x4*)&Bs[kk][tx * 8];
            *(f32x4*)&b[4] = *(const f32x4*)&Bs[kk][tx * 8 + 4];
#pragma unroll
            for (int i = 0; i < 8; ++i)
#pragma unroll
                for (int j = 0; j < 8; ++j) acc[i][j] += a[i] * b[j];
        }
        __syncthreads();
    }
#pragma unroll
    for (int i = 0; i < 8; ++i) {
        int m = m0 + ty * 8 + i;
        if (m < M) {
#pragma unroll
            for (int j = 0; j < 8; ++j) {
                int n = n0 + tx * 8 + j;
                if (n < M) atomicAdd(&C[(size_t)m * M + n], acc[i][j]);
            }
        }
    }
}

// ---------------- bias + relu in place (N = 1024) ----------------------------
__global__ __launch_bounds__(256) void bias_relu_kernel(float* __restrict__ C,
                                                        const float* __restrict__ bias,
                                                        int MN) {
    int i = blockIdx.x * 256 + threadIdx.x;
    if (i < MN) C[i] = fmaxf(C[i] + bias[i & (NH - 1)], 0.0f);
}

// ---------------- row inverse norms of feat ----------------------------------
__global__ __launch_bounds__(256) void norm_kernel(const float* __restrict__ feat,
                                                   float* __restrict__ invn) {
    int s = blockIdx.x;
    int t = threadIdx.x;
    const float* r = feat + (size_t)s * CF;
    float acc = 0.0f;
    for (int c = t * 4; c < CF; c += 1024) {
        f32x4 v = *(const f32x4*)(r + c);
        acc += v.x * v.x + v.y * v.y + v.z * v.z + v.w * v.w;
    }
    for (int off = 32; off; off >>= 1) acc += __shfl_down(acc, off);
    __shared__ float w[4];
    if ((t & 63) == 0) w[t >> 6] = acc;
    __syncthreads();
    if (t == 0) {
        float tot = w[0] + w[1] + w[2] + w[3];
        invn[s] = 1.0f / sqrtf(fmaxf(tot, 1e-30f));
    }
}

// ---------------- fused layer3 + classifier + softmax ------------------------
__global__ __launch_bounds__(256) void head_kernel(const float* __restrict__ h2,
                                                   const float* __restrict__ W3,
                                                   const float* __restrict__ b3,
                                                   const float* __restrict__ Wc,
                                                   const float* __restrict__ bc,
                                                   float* __restrict__ out) {
    int s = blockIdx.x;
    int t = threadIdx.x;
    int d = t & 31, p = t >> 5;   // 8 k-chunks of 128
    const float* row = h2 + (size_t)s * NH;
    float acc = 0.0f;
    int kend = p * 128 + 128;
    for (int k = p * 128; k < kend; ++k) acc += row[k] * W3[k * 32 + d];
    __shared__ float red[8][32];
    __shared__ float h3[32];
    red[p][d] = acc;
    __syncthreads();
    if (t < 32) {
        float v = 0.0f;
#pragma unroll
        for (int q = 0; q < 8; ++q) v += red[q][t];
        v += b3[t];
        h3[t] = fmaxf(v, 0.0f);
    }
    __syncthreads();
    if (t == 0) {
        float l0 = bc[0], l1 = bc[1];
#pragma unroll
        for (int dd = 0; dd < 32; ++dd) {
            l0 += h3[dd] * Wc[2 * dd];
            l1 += h3[dd] * Wc[2 * dd + 1];
        }
        float m  = fmaxf(l0, l1);
        float e0 = expf(l0 - m), e1 = expf(l1 - m);
        float inv = 1.0f / (e0 + e1);
        out[2 * s]     = e0 * inv;
        out[2 * s + 1] = e1 * inv;
    }
}

// ---------------- masked row max/argmax (exp applied inline) -----------------
__global__ void newlab_kernel(const float* __restrict__ dot,
                              const float* __restrict__ invn,
                              const int* __restrict__ lab,
                              float* __restrict__ out) {
    int i    = blockIdx.x;
    int lane = threadIdx.x;
    float im = invn[i];
    float best = -INFINITY;
    int   bidx = 0x7FFFFFFF;
    for (int j = lane; j < NSEG; j += 64) {
        if (lab[j] != 0) {
            float v = expf(-dot[(size_t)i * NSEG + j] * im * invn[j]);
            if (v > best) { best = v; bidx = j; }
        }
    }
    for (int off = 32; off; off >>= 1) {
        float ov = __shfl_down(best, off);
        int   oi = __shfl_down(bidx, off);
        if (ov > best || (ov == best && oi < bidx)) { best = ov; bidx = oi; }
    }
    if (lane == 0) {
        int li = lab[i];
        int nl = li;
        if (li == 0 && best >= 0.7f && bidx != 0x7FFFFFFF) nl = lab[bidx];
        out[880 + i] = (float)nl;
    }
}

extern "C" void kernel_launch(void* const* d_in, const int* in_sizes, int n_in,
                              void* d_out, int out_size, void* d_ws, size_t ws_size,
                              hipStream_t stream) {
    const float* fm = (const float*)d_in[0];
    const int*   sp = (const int*)d_in[1];
    const int*   y  = (const int*)d_in[2];
    const float* W1 = (const float*)d_in[3];
    const float* b1 = (const float*)d_in[4];
    const float* W2 = (const float*)d_in[5];
    const float* b2 = (const float*)d_in[6];
    const float* W3 = (const float*)d_in[7];
    const float* b3 = (const float*)d_in[8];
    const float* Wc = (const float*)d_in[9];
    const float* bc = (const float*)d_in[10];
    float* out = (float*)d_out;
    float* ws  = (float*)d_ws;

    float* hist = ws + OFF_HIST;
    float* dot  = ws + OFF_DOT;
    float* invn = ws + OFF_INVN;
    int*   lab  = (int*)(ws + OFF_LAB);
    float* feat = ws + OFF_FEAT;
    float* h1   = ws + OFF_H1;
    float* h2   = ws + OFF_H2;

    // zero hist+dot (contiguous) and h1+h2 (contiguous)
    hipMemsetAsync(hist, 0, (size_t)(OFF_INVN - OFF_HIST) * 4, stream);
    hipMemsetAsync(h1, 0, (size_t)(450560 * 2) * 4, stream);

    hist_kernel<<<16, 256, 0, stream>>>(sp, y, hist);
    segsum_kernel<<<CF, 256, 0, stream>>>(fm, sp, hist, feat);
    lab_kernel<<<2, 256, 0, stream>>>(hist, lab);
    norm_kernel<<<NSEG, 256, 0, stream>>>(feat, invn);

    // h1 = relu(feat @ W1 + b1): K=2112, split-K 6 x 352
    gemm_nn_atomic<<<dim3(8, 4, 6), 256, 0, stream>>>(feat, W1, h1, NSEG, NH, CF, 352);
    bias_relu_kernel<<<1760, 256, 0, stream>>>(h1, b1, NSEG * NH);
    // h2 = relu(h1 @ W2 + b2): K=1024, split-K 4 x 256
    gemm_nn_atomic<<<dim3(8, 4, 4), 256, 0, stream>>>(h1, W2, h2, NSEG, NH, NH, 256);
    bias_relu_kernel<<<1760, 256, 0, stream>>>(h2, b2, NSEG * NH);
    head_kernel<<<NSEG, 256, 0, stream>>>(h2, W3, b3, Wc, bc, out);

    // dot = feat @ featT: split-K 6 x 352
    gemm_nt_atomic<<<dim3(4, 4, 6), 256, 0, stream>>>(feat, dot, NSEG, CF, 352);
    newlab_kernel<<<NSEG, 64, 0, stream>>>(dot, invn, lab, out);
}